// Round 18
// baseline (123.913 us; speedup 1.0000x reference)
//
#include <hip/hip_runtime.h>

#define HID 50
#define TSTEPS 512

typedef _Float16 h2v __attribute__((ext_vector_type(2)));

__device__ __forceinline__ float fdot2(h2v a, h2v b, float c) {
#if __has_builtin(__builtin_amdgcn_fdot2)
    return __builtin_amdgcn_fdot2(a, b, c, false);
#else
    asm("v_dot2_f32_f16 %0, %1, %2, %0" : "+v"(c) : "v"(a), "v"(b));
    return c;
#endif
}
__device__ __forceinline__ h2v bits_to_h2(unsigned u) {
    h2v r; __builtin_memcpy(&r, &u, sizeof(r)); return r;
}

// Depth-2 pipeline: one wave runs TWO batches (A,B) phase-shifted so each
// batch's LDS broadcast latency (~150cy) is filled by the OTHER batch's
// dot+tanh (~100cy). R16 measured step-slot/wave == chain (264 vs ~260cy):
// co-resident waves were NOT hiding each other's waits, so hide them
// in-wave deterministically. Weights shared across batches (same W!).
// 1024 waves = 1/SIMD; DS load per CU halves vs R16. No barriers: same-wave
// DS ops complete in order (correctness proven R7); h table writes use a
// runtime index so the compiler cannot reorder the (may-aliasing) broadcast
// reads around them. fp16 h + v_dot2_f32_f16 (R16: passed, absmax 2^-7).
__global__ __launch_bounds__(64) __attribute__((amdgpu_waves_per_eu(1, 1)))
void rnn_fused(
    const float* __restrict__ x,      // [B, 512, 1]
    const float* __restrict__ W_ih,   // [50, 1]
    const float* __restrict__ W_hh,   // [50, 50]
    const float* __restrict__ b_ih,   // [50]
    const float* __restrict__ b_hh,   // [50]
    const float* __restrict__ W_fc,   // [1, 50]
    const float* __restrict__ b_fc,   // [1]
    float* __restrict__ out)          // [B, 1]
{
    const int j  = threadIdx.x;       // 0..63; lanes 50..63 duplicate row 0
    const int bA = blockIdx.x * 2;
    const int bB = bA + 1;
    const int jj = (j < HID) ? j : 0;
    const float SC = 2.8853900817779268f;   // 2*log2(e)

    __shared__ __align__(16) _Float16 htA[64], htB[64];
    __shared__ float xbA[64], xbB[64];

    h2v w2[25];
#pragma unroll
    for (int m = 0; m < 25; ++m) {
        h2v t;
        t.x = (_Float16)(W_hh[jj * HID + 2 * m]     * SC);
        t.y = (_Float16)(W_hh[jj * HID + 2 * m + 1] * SC);
        w2[m] = t;
    }
    const float wih  = W_ih[jj] * SC;
    const float btot = (b_ih[jj] + b_hh[jj]) * SC;
    const float wfc  = (j < HID) ? W_fc[jj] : 0.0f;
    const float bfc  = b_fc[0];

    const float* xpA = x + (size_t)bA * TSTEPS;
    const float* xpB = x + (size_t)bB * TSTEPS;
    float xvA = xpA[j], xvB = xpB[j];
    float hnA = 0.0f, hnB = 0.0f;

    // prologue: h0 tables + B's first quad set (h0 = 0)
    htA[j] = (_Float16)0.0f;
    htB[j] = (_Float16)0.0f;
    const uint4* qA = reinterpret_cast<const uint4*>(htA);
    const uint4* qB = reinterpret_cast<const uint4*>(htB);
    uint4 qb[7];
#pragma unroll
    for (int q = 0; q < 7; ++q) qb[q] = qB[q];

    for (int c = 0; c < TSTEPS / 64; ++c) {
        xbA[j] = xvA;                 // stage chunk (same-wave in-order DS)
        xbB[j] = xvB;
        float xnA = 0.0f, xnB = 0.0f;
        if (c + 1 < TSTEPS / 64) {
            xnA = xpA[(c + 1) * 64 + j];
            xnB = xpB[(c + 1) * 64 + j];
        }

        for (int g = 0; g < 8; ++g) {
#pragma unroll
            for (int ii = 0; ii < 8; ++ii) {
                const int t = g * 8 + ii;

                // ---- phase 1: publish A's h(t), issue A's broadcast reads
                htA[j] = (_Float16)hnA;
                uint4 qa[7];
#pragma unroll
                for (int q = 0; q < 7; ++q) qa[q] = qA[q];
                const float xtA = xbA[t];
                const float xtB = xbB[t];
                __builtin_amdgcn_sched_barrier(0);

                // ---- phase 2: B's dot from LAST superstep's quads (qb);
                //      fills A's read latency. Then publish B, issue B reads.
                {
                    float a0 = fmaf(xtB, wih, btot), a1 = 0.f, a2 = 0.f, a3 = 0.f;
#pragma unroll
                    for (int q = 0; q < 7; ++q) {
                        const int m = 4 * q;
                        a0 = fdot2(bits_to_h2(qb[q].x), w2[m], a0);
                        if (m + 1 < 25) a1 = fdot2(bits_to_h2(qb[q].y), w2[m + 1], a1);
                        if (m + 2 < 25) a2 = fdot2(bits_to_h2(qb[q].z), w2[m + 2], a2);
                        if (m + 3 < 25) a3 = fdot2(bits_to_h2(qb[q].w), w2[m + 3], a3);
                    }
                    const float z = (a0 + a1) + (a2 + a3);
                    const float e = __builtin_amdgcn_exp2f(z);
                    hnB = fmaf(-2.0f, __builtin_amdgcn_rcpf(e + 1.0f), 1.0f);
                }
                htB[j] = (_Float16)hnB;
#pragma unroll
                for (int q = 0; q < 7; ++q) qb[q] = qB[q];
                __builtin_amdgcn_sched_barrier(0);

                // ---- phase 3: A's dot from qa (reads have landed; B's
                //      compute covered them). Fills B's read latency.
                {
                    float a0 = fmaf(xtA, wih, btot), a1 = 0.f, a2 = 0.f, a3 = 0.f;
#pragma unroll
                    for (int q = 0; q < 7; ++q) {
                        const int m = 4 * q;
                        a0 = fdot2(bits_to_h2(qa[q].x), w2[m], a0);
                        if (m + 1 < 25) a1 = fdot2(bits_to_h2(qa[q].y), w2[m + 1], a1);
                        if (m + 2 < 25) a2 = fdot2(bits_to_h2(qa[q].z), w2[m + 2], a2);
                        if (m + 3 < 25) a3 = fdot2(bits_to_h2(qa[q].w), w2[m + 3], a3);
                    }
                    const float z = (a0 + a1) + (a2 + a3);
                    const float e = __builtin_amdgcn_exp2f(z);
                    hnA = fmaf(-2.0f, __builtin_amdgcn_rcpf(e + 1.0f), 1.0f);
                }
            }
        }
        xvA = xnA;
        xvB = xnB;
    }

    // out[b] = sum_j h_T[j]*W_fc[j] + b_fc for both batches
    float pA = hnA * wfc, pB = hnB * wfc;
#pragma unroll
    for (int off = 32; off >= 1; off >>= 1) {
        pA += __shfl_xor(pA, off);
        pB += __shfl_xor(pB, off);
    }
    if (j == 0) {
        out[bA] = pA + bfc;
        out[bB] = pB + bfc;
    }
}

extern "C" void kernel_launch(void* const* d_in, const int* in_sizes, int n_in,
                              void* d_out, int out_size, void* d_ws, size_t ws_size,
                              hipStream_t stream) {
    (void)d_ws; (void)ws_size; (void)n_in; (void)out_size;
    const float* x    = (const float*)d_in[0];
    const float* W_ih = (const float*)d_in[1];
    const float* W_hh = (const float*)d_in[2];
    const float* b_ih = (const float*)d_in[3];
    const float* b_hh = (const float*)d_in[4];
    const float* W_fc = (const float*)d_in[5];
    const float* b_fc = (const float*)d_in[6];
    float* out = (float*)d_out;

    const int B = in_sizes[0] / TSTEPS;   // 2048
    rnn_fused<<<dim3(B / 2), dim3(64), 0, stream>>>(x, W_ih, W_hh, b_ih, b_hh,
                                                    W_fc, b_fc, out);
}

// Round 19
// 120.637 us; speedup vs baseline: 1.0272x; 1.0272x over previous
//
#include <hip/hip_runtime.h>

#define HID 50
#define TSTEPS 512

typedef _Float16 h2v __attribute__((ext_vector_type(2)));

__device__ __forceinline__ float fdot2(h2v a, h2v b, float c) {
#if __has_builtin(__builtin_amdgcn_fdot2)
    return __builtin_amdgcn_fdot2(a, b, c, false);
#else
    asm("v_dot2_f32_f16 %0, %1, %2, %0" : "+v"(c) : "v"(a), "v"(b));
    return c;
#endif
}
__device__ __forceinline__ h2v bits_to_h2(unsigned u) {
    h2v r; __builtin_memcpy(&r, &u, sizeof(r)); return r;
}

// Depth-2 pipeline, R18 + the waitcnt-ordering fix.
// R18 failed because the xt reads were issued LAST and used FIRST ->
// s_waitcnt lgkmcnt(0) drained the whole DS queue (in-order completion),
// serializing both chains (628cy superstep = 320 issue + 2x150 chain).
// Fix: xt reads issued FIRST (oldest in queue), consumed LAST (x-projection
// folded in at the end: z = fma(xt, wih, dots)). All waits become counted
// (lgkmcnt(8..10)), the qa/qb broadcast reads stay in flight across phases,
// and each batch's ~150cy LDS chain is covered by the other batch's ~110cy
// dot+tanh. fp16 h + v_dot2_f32_f16 (R16: passed, absmax 2^-7).
__global__ __launch_bounds__(64) __attribute__((amdgpu_waves_per_eu(1, 1)))
void rnn_fused(
    const float* __restrict__ x,      // [B, 512, 1]
    const float* __restrict__ W_ih,   // [50, 1]
    const float* __restrict__ W_hh,   // [50, 50]
    const float* __restrict__ b_ih,   // [50]
    const float* __restrict__ b_hh,   // [50]
    const float* __restrict__ W_fc,   // [1, 50]
    const float* __restrict__ b_fc,   // [1]
    float* __restrict__ out)          // [B, 1]
{
    const int j  = threadIdx.x;       // 0..63; lanes 50..63 duplicate row 0
    const int bA = blockIdx.x * 2;
    const int bB = bA + 1;
    const int jj = (j < HID) ? j : 0;
    const float SC = 2.8853900817779268f;   // 2*log2(e)

    __shared__ __align__(16) _Float16 htA[64], htB[64];
    __shared__ float xbA[64], xbB[64];

    h2v w2[25];
#pragma unroll
    for (int m = 0; m < 25; ++m) {
        h2v t;
        t.x = (_Float16)(W_hh[jj * HID + 2 * m]     * SC);
        t.y = (_Float16)(W_hh[jj * HID + 2 * m + 1] * SC);
        w2[m] = t;
    }
    const float wih  = W_ih[jj] * SC;
    const float btot = (b_ih[jj] + b_hh[jj]) * SC;
    const float wfc  = (j < HID) ? W_fc[jj] : 0.0f;
    const float bfc  = b_fc[0];

    const float* xpA = x + (size_t)bA * TSTEPS;
    const float* xpB = x + (size_t)bB * TSTEPS;
    float xvA = xpA[j], xvB = xpB[j];
    float hnA = 0.0f, hnB = 0.0f;

    // prologue: h0 tables + B's first quad set (h0 = 0)
    htA[j] = (_Float16)0.0f;
    htB[j] = (_Float16)0.0f;
    const uint4* qA = reinterpret_cast<const uint4*>(htA);
    const uint4* qB = reinterpret_cast<const uint4*>(htB);
    uint4 qb[7];
#pragma unroll
    for (int q = 0; q < 7; ++q) qb[q] = qB[q];

    for (int c = 0; c < TSTEPS / 64; ++c) {
        xbA[j] = xvA;                 // stage chunk (same-wave in-order DS)
        xbB[j] = xvB;
        float xnA = 0.0f, xnB = 0.0f;
        if (c + 1 < TSTEPS / 64) {
            xnA = xpA[(c + 1) * 64 + j];
            xnB = xpB[(c + 1) * 64 + j];
        }

        for (int g = 0; g < 8; ++g) {
#pragma unroll
            for (int ii = 0; ii < 8; ++ii) {
                const int t = g * 8 + ii;

                // ---- phase 1: xt reads FIRST (oldest in DS queue, consumed
                //      last), then publish A's h(t), then A's broadcast reads.
                const float xtA = xbA[t];
                const float xtB = xbB[t];
                htA[j] = (_Float16)hnA;
                uint4 qa[7];
#pragma unroll
                for (int q = 0; q < 7; ++q) qa[q] = qA[q];
                __builtin_amdgcn_sched_barrier(0);

                // ---- phase 2: B's dot from LAST superstep's quads (qb);
                //      covers A's reads. xtB folded in at the END.
                {
                    float a0 = btot, a1 = 0.f, a2 = 0.f, a3 = 0.f;
#pragma unroll
                    for (int q = 0; q < 7; ++q) {
                        const int m = 4 * q;
                        a0 = fdot2(bits_to_h2(qb[q].x), w2[m], a0);
                        if (m + 1 < 25) a1 = fdot2(bits_to_h2(qb[q].y), w2[m + 1], a1);
                        if (m + 2 < 25) a2 = fdot2(bits_to_h2(qb[q].z), w2[m + 2], a2);
                        if (m + 3 < 25) a3 = fdot2(bits_to_h2(qb[q].w), w2[m + 3], a3);
                    }
                    const float z = fmaf(xtB, wih, (a0 + a1) + (a2 + a3));
                    const float e = __builtin_amdgcn_exp2f(z);
                    hnB = fmaf(-2.0f, __builtin_amdgcn_rcpf(e + 1.0f), 1.0f);
                }
                htB[j] = (_Float16)hnB;
#pragma unroll
                for (int q = 0; q < 7; ++q) qb[q] = qB[q];
                __builtin_amdgcn_sched_barrier(0);

                // ---- phase 3: A's dot from qa (covered by phase 2's
                //      compute); xtA folded in at the END.
                {
                    float a0 = btot, a1 = 0.f, a2 = 0.f, a3 = 0.f;
#pragma unroll
                    for (int q = 0; q < 7; ++q) {
                        const int m = 4 * q;
                        a0 = fdot2(bits_to_h2(qa[q].x), w2[m], a0);
                        if (m + 1 < 25) a1 = fdot2(bits_to_h2(qa[q].y), w2[m + 1], a1);
                        if (m + 2 < 25) a2 = fdot2(bits_to_h2(qa[q].z), w2[m + 2], a2);
                        if (m + 3 < 25) a3 = fdot2(bits_to_h2(qa[q].w), w2[m + 3], a3);
                    }
                    const float z = fmaf(xtA, wih, (a0 + a1) + (a2 + a3));
                    const float e = __builtin_amdgcn_exp2f(z);
                    hnA = fmaf(-2.0f, __builtin_amdgcn_rcpf(e + 1.0f), 1.0f);
                }
            }
        }
        xvA = xnA;
        xvB = xnB;
    }

    // out[b] = sum_j h_T[j]*W_fc[j] + b_fc for both batches
    float pA = hnA * wfc, pB = hnB * wfc;
#pragma unroll
    for (int off = 32; off >= 1; off >>= 1) {
        pA += __shfl_xor(pA, off);
        pB += __shfl_xor(pB, off);
    }
    if (j == 0) {
        out[bA] = pA + bfc;
        out[bB] = pB + bfc;
    }
}

extern "C" void kernel_launch(void* const* d_in, const int* in_sizes, int n_in,
                              void* d_out, int out_size, void* d_ws, size_t ws_size,
                              hipStream_t stream) {
    (void)d_ws; (void)ws_size; (void)n_in; (void)out_size;
    const float* x    = (const float*)d_in[0];
    const float* W_ih = (const float*)d_in[1];
    const float* W_hh = (const float*)d_in[2];
    const float* b_ih = (const float*)d_in[3];
    const float* b_hh = (const float*)d_in[4];
    const float* W_fc = (const float*)d_in[5];
    const float* b_fc = (const float*)d_in[6];
    float* out = (float*)d_out;

    const int B = in_sizes[0] / TSTEPS;   // 2048
    rnn_fused<<<dim3(B / 2), dim3(64), 0, stream>>>(x, W_ih, W_hh, b_ih, b_hh,
                                                    W_fc, b_fc, out);
}